// Round 1
// baseline (132.837 us; speedup 1.0000x reference)
//
#include <hip/hip_runtime.h>
#include <stdint.h>

// covpool: y[b] = (1/M) Xc Xc^T = (1/256)(X X^T) - mu mu^T   (M=256)
// One fused kernel. Upper-triangular tiles only (y symmetric): 10 tiles/batch,
// off-diag blocks store both orientations via an LDS transpose buffer.
// K-loop register-prefetches the next chunk so global latency overlaps MFMA.
// Staging converts f32->bf16 via v_cvt_pk_bf16_f32 (RNE, 2 elem/instr); the
// 1/16 pre-scale is folded into the epilogue (pure exponent shift in bf16).

typedef __attribute__((ext_vector_type(8))) short bf16x8;   // 8 bf16 = 4 VGPRs
typedef __attribute__((ext_vector_type(4))) float f32x4;
typedef __attribute__((ext_vector_type(4))) unsigned int u32x4;

static __device__ __forceinline__ uint32_t cvtpk(float a, float b) {
    uint32_t r;
    asm("v_cvt_pk_bf16_f32 %0, %1, %2" : "=v"(r) : "v"(a), "v"(b));
    return r;  // lo16 = bf16(a), hi16 = bf16(b) (order is dot-product-invariant:
               // A and B stage through the same permutation)
}

static __device__ __forceinline__ void stage8(f32x4 v0, f32x4 v1, float* psum,
                                              unsigned short* dst) {
    *psum += (v0.x + v0.y + v0.z + v0.w) + (v1.x + v1.y + v1.z + v1.w);
    u32x4 o;
    o.x = cvtpk(v0.x, v0.y);
    o.y = cvtpk(v0.z, v0.w);
    o.z = cvtpk(v1.x, v1.y);
    o.w = cvtpk(v1.z, v1.w);
    *(u32x4*)dst = o;
}

__global__ __launch_bounds__(256, 3) void covpool_fused(const float* __restrict__ x,
                                                        float* __restrict__ y) {
    __shared__ __align__(16) unsigned short As[128 * 32];  // [row][slot], slot=chunk^((row>>1)&3)
    __shared__ __align__(16) unsigned short Bs[128 * 32];
    __shared__ __align__(16) float Ep[32 * 132];           // epilogue transpose buffer
    __shared__ float muA[128];
    __shared__ float muB[128];

    // 640 blocks: XCD swizzle (blockIdx%8 -> XCD), 8 batches/XCD x 10 upper-tri tiles
    const int xcd = blockIdx.x & 7;
    const int j   = blockIdx.x >> 3;         // 0..79
    const int b   = xcd * 8 + j / 10;        // 0..63
    const int t10 = j % 10;
    // nibble LUT: t10 -> (tm<<2|tn) over {(0,0)..(3,3), tm<=tn}
    const unsigned code = (unsigned)((0xFBA7653210ULL >> (4 * t10)) & 15ULL);
    const int tm = code >> 2, tn = code & 3;
    const bool diag = (tm == tn);

    const float* Ag = x + ((size_t)b * 512 + tm * 128) * 256;
    const float* Bg = x + ((size_t)b * 512 + tn * 128) * 256;

    const int tid  = threadIdx.x;
    const int lane = tid & 63;
    const int wave = tid >> 6;
    const int wm = (wave >> 1) * 64;
    const int wn = (wave & 1) * 64;

    f32x4 acc[4][4] = {};
    float pA[2] = {0.f, 0.f}, pB[2] = {0.f, 0.f};

    const int rl  = lane & 15;
    const int q   = lane >> 4;
    const int swl = (q ^ ((rl >> 1) & 3)) * 8;   // swizzled read slot (shorts)
    const int srow = tid >> 2, schunk = tid & 3;

    // prefetch kk=0 into registers
    f32x4 a0[2], a1[2], b0[2], b1[2];
#pragma unroll
    for (int t = 0; t < 2; ++t) {
        const float* g = Ag + (size_t)(t * 64 + srow) * 256 + schunk * 8;
        a0[t] = *(const f32x4*)g; a1[t] = *(const f32x4*)(g + 4);
        if (!diag) {
            const float* h = Bg + (size_t)(t * 64 + srow) * 256 + schunk * 8;
            b0[t] = *(const f32x4*)h; b1[t] = *(const f32x4*)(h + 4);
        }
    }

    for (int kk = 0; kk < 256; kk += 32) {
        __syncthreads();                     // prev iter's fragment reads done
#pragma unroll
        for (int t = 0; t < 2; ++t) {
            const int row  = t * 64 + srow;
            const int slot = schunk ^ ((row >> 1) & 3);
            stage8(a0[t], a1[t], &pA[t], As + row * 32 + slot * 8);
            if (!diag) stage8(b0[t], b1[t], &pB[t], Bs + row * 32 + slot * 8);
        }
        __syncthreads();
        if (kk < 224) {                      // issue next chunk; waited at next stage8
#pragma unroll
            for (int t = 0; t < 2; ++t) {
                const float* g = Ag + (size_t)(t * 64 + srow) * 256 + (kk + 32) + schunk * 8;
                a0[t] = *(const f32x4*)g; a1[t] = *(const f32x4*)(g + 4);
                if (!diag) {
                    const float* h = Bg + (size_t)(t * 64 + srow) * 256 + (kk + 32) + schunk * 8;
                    b0[t] = *(const f32x4*)h; b1[t] = *(const f32x4*)(h + 4);
                }
            }
        }
        const unsigned short* Bsrc = diag ? As : Bs;
        bf16x8 bfr[4];
#pragma unroll
        for (int jj = 0; jj < 4; ++jj)
            bfr[jj] = *(const bf16x8*)(Bsrc + (wn + jj * 16 + rl) * 32 + swl);
#pragma unroll
        for (int i = 0; i < 4; ++i) {
            const bf16x8 af = *(const bf16x8*)(As + (wm + i * 16 + rl) * 32 + swl);
#pragma unroll
            for (int jj = 0; jj < 4; ++jj)
                acc[i][jj] = __builtin_amdgcn_mfma_f32_16x16x32_bf16(
                    af, bfr[jj], acc[i][jj], 0, 0, 0);
        }
    }

    // row means: 4 staging threads per row; staged vals are raw x so mu = rowsum/256
#pragma unroll
    for (int t = 0; t < 2; ++t) {
        float s = pA[t];
        s += __shfl_xor(s, 1, 64); s += __shfl_xor(s, 2, 64);
        if (schunk == 0) muA[t * 64 + srow] = s * (1.0f / 256.0f);
        if (!diag) {
            float sb = pB[t];
            sb += __shfl_xor(sb, 1, 64); sb += __shfl_xor(sb, 2, 64);
            if (schunk == 0) muB[t * 64 + srow] = sb * (1.0f / 256.0f);
        }
    }
    const float* muBp = diag ? muA : muB;
    float* yb = y + (size_t)b * 512 * 512;
    const float inv256 = 1.0f / 256.0f;

    // Epilogue in 4 chunks of 32 rows through Ep[32][132]:
    //   owner waves (wm matching) write acc/256 - mu_r*mu_c; all waves store coalesced
    //   f32x4 runs, plus the transposed (mirror) tile for off-diag blocks.
#pragma unroll
    for (int c = 0; c < 4; ++c) {
        __syncthreads();                     // Ep free; mu ready (first iter)
        if ((wave >> 1) == (c >> 1)) {       // rows 32c..32c+31 live in this wave's acc
            const int ii0 = 2 * (c & 1);
#pragma unroll
            for (int ii = 0; ii < 2; ++ii) {
                const int i = ii0 + ii;
#pragma unroll
                for (int jj = 0; jj < 4; ++jj) {
                    const int col = wn + jj * 16 + rl;
                    const float mb = muBp[col];
#pragma unroll
                    for (int r = 0; r < 4; ++r) {
                        const int row = wm + i * 16 + q * 4 + r;
                        Ep[(ii * 16 + q * 4 + r) * 132 + col] =
                            acc[i][jj][r] * inv256 - muA[row] * mb;
                    }
                }
            }
        }
        __syncthreads();
        // normal orientation: 512B-contiguous dwordx4 runs
#pragma unroll
        for (int v = 0; v < 4; ++v) {
            const int flat = v * 256 + tid;          // 0..1023
            const int rloc = flat >> 5, c4 = flat & 31;
            f32x4 val = *(const f32x4*)(Ep + rloc * 132 + c4 * 4);
            *(f32x4*)(yb + (size_t)(tm * 128 + c * 32 + rloc) * 512 + tn * 128 + c4 * 4) = val;
        }
        if (!diag) {  // mirror: y[col][row] = same value, read Ep transposed
#pragma unroll
            for (int v = 0; v < 4; ++v) {
                const int id = v * 256 + tid;        // 0..1023
                const int cc = id >> 3, g = id & 7;  // cc: tile col, g: 4-row group
                f32x4 val;
#pragma unroll
                for (int e = 0; e < 4; ++e)
                    val[e] = Ep[(g * 4 + e) * 132 + cc];
                *(f32x4*)(yb + (size_t)(tn * 128 + cc) * 512 + tm * 128 + c * 32 + g * 4) = val;
            }
        }
    }
}

extern "C" void kernel_launch(void* const* d_in, const int* in_sizes, int n_in,
                              void* d_out, int out_size, void* d_ws, size_t ws_size,
                              hipStream_t stream) {
    const float* x = (const float*)d_in[0];
    float* yout = (float*)d_out;
    (void)d_ws; (void)ws_size;
    covpool_fused<<<640, 256, 0, stream>>>(x, yout);
}

// Round 2
// 111.979 us; speedup vs baseline: 1.1863x; 1.1863x over previous
//
#include <hip/hip_runtime.h>
#include <stdint.h>

// covpool: y[b] = (1/M) Xc Xc^T = (1/16 X)(1/16 X)^T - mu mu^T   (M=256)
// One fused kernel. Upper-triangular tiles only (y symmetric): 10 tiles/batch,
// off-diag blocks store both orientations via an LDS transpose buffer.
// K-loop register-prefetches the next chunk so global latency overlaps MFMA.
//
// Round-2 restructure: 512-thread blocks (8 waves, 32x64 acc each) instead of
// 256 (4 waves, 64x64). Halves per-wave VGPR demand (acc 32 vs 64) so 2 blocks
// (16 waves/CU) fit naturally under the 128-VGPR cliff -> 2x resident waves to
// hide L2/LLC latency + barrier drains. Round-1 lessons reverted: manual RNE
// (no inline-asm cvt_pk, m240), no tight launch_bounds VGPR squeeze.

typedef __attribute__((ext_vector_type(8))) short bf16x8;   // 8 bf16 = 4 VGPRs
typedef __attribute__((ext_vector_type(4))) float f32x4;

static __device__ __forceinline__ unsigned short f2bf(float f) {
    union { float f; uint32_t u; } c; c.f = f;
    uint32_t u = c.u;
    return (unsigned short)((u + 0x7FFFu + ((u >> 16) & 1u)) >> 16);  // RNE
}

static __device__ __forceinline__ void cvt_store(f32x4 v0, f32x4 v1, float* psum,
                                                 unsigned short* dst) {
    v0 *= 0.0625f; v1 *= 0.0625f;
    *psum += (v0.x + v0.y + v0.z + v0.w) + (v1.x + v1.y + v1.z + v1.w);
    bf16x8 o;
    o[0] = (short)f2bf(v0.x); o[1] = (short)f2bf(v0.y);
    o[2] = (short)f2bf(v0.z); o[3] = (short)f2bf(v0.w);
    o[4] = (short)f2bf(v1.x); o[5] = (short)f2bf(v1.y);
    o[6] = (short)f2bf(v1.z); o[7] = (short)f2bf(v1.w);
    *(bf16x8*)dst = o;
}

__global__ __launch_bounds__(512, 4) void covpool_fused(const float* __restrict__ x,
                                                        float* __restrict__ y) {
    __shared__ __align__(16) unsigned short As[128 * 32];  // [row][slot], slot=chunk^((row>>1)&3)
    __shared__ __align__(16) unsigned short Bs[128 * 32];
    __shared__ __align__(16) float Ep[32 * 132];           // epilogue transpose buffer
    __shared__ float muA[128];
    __shared__ float muB[128];

    // 640 blocks: XCD swizzle (blockIdx%8 -> XCD), 8 batches/XCD x 10 upper-tri tiles
    const int xcd = blockIdx.x & 7;
    const int j   = blockIdx.x >> 3;         // 0..79
    const int b   = xcd * 8 + j / 10;        // 0..63
    const int t10 = j % 10;
    // nibble LUT: t10 -> (tm<<2|tn) over {(0,0)..(3,3), tm<=tn}
    const unsigned code = (unsigned)((0xFBA7653210ULL >> (4 * t10)) & 15ULL);
    const int tm = code >> 2, tn = code & 3;
    const bool diag = (tm == tn);

    const float* Ag = x + ((size_t)b * 512 + tm * 128) * 256;
    const float* Bg = x + ((size_t)b * 512 + tn * 128) * 256;

    const int tid  = threadIdx.x;
    const int lane = tid & 63;
    const int wave = tid >> 6;               // 0..7
    const int wm = (wave >> 1) * 32;         // 0,32,64,96 (row sub-tile)
    const int wn = (wave & 1) * 64;          // 0,64       (col sub-tile)

    f32x4 acc[2][4] = {};
    float pA = 0.f, pB = 0.f;

    const int rl  = lane & 15;
    const int q   = lane >> 4;
    const int swl = (q ^ ((rl >> 1) & 3)) * 8;   // swizzled read slot (shorts)
    const int srow = tid >> 2, schunk = tid & 3; // srow 0..127: one staging row/thread
    const int slot = schunk ^ ((srow >> 1) & 3);
    unsigned short* Adst = As + srow * 32 + slot * 8;
    unsigned short* Bdst = Bs + srow * 32 + slot * 8;
    const float* Asrc = Ag + (size_t)srow * 256 + schunk * 8;
    const float* Bsrc = Bg + (size_t)srow * 256 + schunk * 8;

    // prefetch kk=0 into registers
    f32x4 a0, a1, b0, b1;
    a0 = *(const f32x4*)Asrc; a1 = *(const f32x4*)(Asrc + 4);
    if (!diag) { b0 = *(const f32x4*)Bsrc; b1 = *(const f32x4*)(Bsrc + 4); }

    for (int kk = 0; kk < 256; kk += 32) {
        __syncthreads();                     // prev iter's fragment reads done
        cvt_store(a0, a1, &pA, Adst);
        if (!diag) cvt_store(b0, b1, &pB, Bdst);
        __syncthreads();
        if (kk < 224) {                      // issue next chunk; waited at next cvt_store
            a0 = *(const f32x4*)(Asrc + kk + 32);
            a1 = *(const f32x4*)(Asrc + kk + 36);
            if (!diag) {
                b0 = *(const f32x4*)(Bsrc + kk + 32);
                b1 = *(const f32x4*)(Bsrc + kk + 36);
            }
        }
        const unsigned short* Bsr = diag ? As : Bs;
        bf16x8 af[2], bfr[4];
#pragma unroll
        for (int i = 0; i < 2; ++i)
            af[i] = *(const bf16x8*)(As + (wm + i * 16 + rl) * 32 + swl);
#pragma unroll
        for (int jj = 0; jj < 4; ++jj)
            bfr[jj] = *(const bf16x8*)(Bsr + (wn + jj * 16 + rl) * 32 + swl);
#pragma unroll
        for (int i = 0; i < 2; ++i)
#pragma unroll
            for (int jj = 0; jj < 4; ++jj)
                acc[i][jj] = __builtin_amdgcn_mfma_f32_16x16x32_bf16(
                    af[i], bfr[jj], acc[i][jj], 0, 0, 0);
    }

    // row means: 4 staging threads per row; staged vals are x/16 so mu = rowsum/16
    {
        float s = pA;
        s += __shfl_xor(s, 1, 64); s += __shfl_xor(s, 2, 64);
        if (schunk == 0) muA[srow] = s * 0.0625f;
        if (!diag) {
            float sb = pB;
            sb += __shfl_xor(sb, 1, 64); sb += __shfl_xor(sb, 2, 64);
            if (schunk == 0) muB[srow] = sb * 0.0625f;
        }
    }
    const float* muBp = diag ? muA : muB;
    float* yb = y + (size_t)b * 512 * 512;

    // Epilogue in 4 chunks of 32 rows through Ep[32][132]:
    //   owner wave-pair (wave>>1 == c) writes acc - mu_r*mu_c; all waves store
    //   coalesced f32x4 runs, plus the transposed (mirror) tile for off-diag.
#pragma unroll
    for (int c = 0; c < 4; ++c) {
        __syncthreads();                     // Ep free; mu ready (first iter)
        if ((wave >> 1) == c) {              // rows 32c..32c+31 live in this wave's acc
#pragma unroll
            for (int i = 0; i < 2; ++i) {
#pragma unroll
                for (int jj = 0; jj < 4; ++jj) {
                    const int col = wn + jj * 16 + rl;
                    const float mb = muBp[col];
#pragma unroll
                    for (int r = 0; r < 4; ++r) {
                        const int row = wm + i * 16 + q * 4 + r;
                        Ep[(i * 16 + q * 4 + r) * 132 + col] = acc[i][jj][r] - muA[row] * mb;
                    }
                }
            }
        }
        __syncthreads();
        // normal orientation: 512B-contiguous dwordx4 runs
#pragma unroll
        for (int v = 0; v < 2; ++v) {
            const int flat = v * 512 + tid;          // 0..1023
            const int rloc = flat >> 5, c4 = flat & 31;
            f32x4 val = *(const f32x4*)(Ep + rloc * 132 + c4 * 4);
            *(f32x4*)(yb + (size_t)(tm * 128 + c * 32 + rloc) * 512 + tn * 128 + c4 * 4) = val;
        }
        if (!diag) {  // mirror: y[col][row] = same value, read Ep transposed
#pragma unroll
            for (int v = 0; v < 2; ++v) {
                const int id = v * 512 + tid;        // 0..1023
                const int cc = id >> 3, g = id & 7;  // cc: tile col, g: 4-row group
                f32x4 val;
#pragma unroll
                for (int e = 0; e < 4; ++e)
                    val[e] = Ep[(g * 4 + e) * 132 + cc];
                *(f32x4*)(yb + (size_t)(tn * 128 + cc) * 512 + tm * 128 + c * 32 + g * 4) = val;
            }
        }
    }
}

extern "C" void kernel_launch(void* const* d_in, const int* in_sizes, int n_in,
                              void* d_out, int out_size, void* d_ws, size_t ws_size,
                              hipStream_t stream) {
    const float* x = (const float*)d_in[0];
    float* yout = (float*)d_out;
    (void)d_ws; (void)ws_size;
    covpool_fused<<<640, 512, 0, stream>>>(x, yout);
}

// Round 3
// 107.559 us; speedup vs baseline: 1.2350x; 1.0411x over previous
//
#include <hip/hip_runtime.h>
#include <stdint.h>

// covpool: y[b] = (1/M) Xc Xc^T = (1/256)(X X^T) - mu mu^T   (M=256)
// Upper-triangular tiles only (10 blocks/batch); off-diag blocks emit both
// orientations via an LDS transpose buffer.
//
// Round-3 restructure (schedule, not occupancy — rounds 1/2 showed occupancy
// isn't the limiter):
//  * Double-buffered As/Bs K-loop: ONE barrier per K-iter (was 2), staging of
//    tile k+1 happens AFTER the MFMAs of tile k, so the LDS write->read dep
//    crosses the barrier instead of serializing inside the iteration.
//  * Raw s_barrier + explicit lgkmcnt(0) instead of __syncthreads: no vmcnt
//    drains at barriers. Safe: no cross-wave hazard here involves vmem (x is
//    read-only, y is write-only) -> prefetch loads stay in flight across
//    barriers, epilogue stores stream without drains.
//  * Single-pass epilogue: full 128x132 f32 Ep unioned over the staging LDS
//    (never live simultaneously) -> 2 epilogue barriers (was 8), all 16(+16)
//    f32x4 stores per thread issued back-to-back, nontemporal (y write-once,
//    keeps x L2-resident).
//  * 1/16 pre-scale folded into epilogue (1/256): exponent-only, bitwise-same
//    bf16 mantissas; saves 8 v_mul per stage call.
// 256 threads, acc[4][4]/wave, launch_bounds(256,2): VGPR cap 256 (no spill —
// round 1/2 lesson), LDS 68.6KB -> 2 blocks/CU.

typedef __attribute__((ext_vector_type(8))) short bf16x8;   // 8 bf16 = 4 VGPRs
typedef __attribute__((ext_vector_type(4))) float f32x4;

static __device__ __forceinline__ unsigned short f2bf(float f) {
    union { float f; uint32_t u; } c; c.f = f;
    uint32_t u = c.u;
    return (unsigned short)((u + 0x7FFFu + ((u >> 16) & 1u)) >> 16);  // RNE
}

static __device__ __forceinline__ void cvt_store(f32x4 v0, f32x4 v1, float* psum,
                                                 unsigned short* dst) {
    *psum += (v0.x + v0.y + v0.z + v0.w) + (v1.x + v1.y + v1.z + v1.w);
    bf16x8 o;
    o[0] = (short)f2bf(v0.x); o[1] = (short)f2bf(v0.y);
    o[2] = (short)f2bf(v0.z); o[3] = (short)f2bf(v0.w);
    o[4] = (short)f2bf(v1.x); o[5] = (short)f2bf(v1.y);
    o[6] = (short)f2bf(v1.z); o[7] = (short)f2bf(v1.w);
    *(bf16x8*)dst = o;
}

// LDS barrier: drain own LDS ops (write visibility / read-before-overwrite),
// cross the barrier, fence the compiler. Deliberately NO vmcnt drain.
static __device__ __forceinline__ void bar_lds() {
    asm volatile("s_waitcnt lgkmcnt(0)" ::: "memory");
    __builtin_amdgcn_s_barrier();
    asm volatile("" ::: "memory");
}

__global__ __launch_bounds__(256, 2) void covpool_fused(const float* __restrict__ x,
                                                        float* __restrict__ y) {
    // union region: K-loop staging (32KB: As[2]+Bs[2] bf16) / epilogue Ep[128][132] f32
    __shared__ __align__(16) float shf[128 * 132];
    __shared__ float muA[128];
    __shared__ float muB[128];
    unsigned short* const Sbase = (unsigned short*)shf;  // As: [buf*4096], Bs: [8192+buf*4096]

    // 640 blocks: XCD swizzle (blockIdx%8 -> XCD), 8 batches/XCD x 10 upper-tri tiles
    const int xcd = blockIdx.x & 7;
    const int j   = blockIdx.x >> 3;         // 0..79
    const int b   = xcd * 8 + j / 10;        // 0..63
    const int t10 = j % 10;
    // nibble LUT: t10 -> (tm<<2|tn) over {(0,0)..(3,3), tm<=tn}
    const unsigned code = (unsigned)((0xFBA7653210ULL >> (4 * t10)) & 15ULL);
    const int tm = code >> 2, tn = code & 3;
    const bool diag = (tm == tn);

    const float* Ag = x + ((size_t)b * 512 + tm * 128) * 256;
    const float* Bg = x + ((size_t)b * 512 + tn * 128) * 256;

    const int tid  = threadIdx.x;
    const int lane = tid & 63;
    const int wave = tid >> 6;
    const int wm = (wave >> 1) * 64;
    const int wn = (wave & 1) * 64;

    f32x4 acc[4][4] = {};
    float pA[2] = {0.f, 0.f}, pB[2] = {0.f, 0.f};

    const int rl  = lane & 15;
    const int q   = lane >> 4;
    const int swl = (q ^ ((rl >> 1) & 3)) * 8;   // swizzled read slot (shorts)
    const int srow = tid >> 2, schunk = tid & 3; // srow 0..63 (+64 via t)
    const int slot = schunk ^ ((srow >> 1) & 3); // t-independent ((row>>1)&3 same for row, row+64)

    // ---- prologue: load+stage tile 0 into buf0, issue loads for tile 1 ----
    f32x4 a0[2], a1[2], b0[2], b1[2];
#pragma unroll
    for (int t = 0; t < 2; ++t) {
        const float* g = Ag + (size_t)(t * 64 + srow) * 256 + schunk * 8;
        a0[t] = *(const f32x4*)g; a1[t] = *(const f32x4*)(g + 4);
        if (!diag) {
            const float* h = Bg + (size_t)(t * 64 + srow) * 256 + schunk * 8;
            b0[t] = *(const f32x4*)h; b1[t] = *(const f32x4*)(h + 4);
        }
    }
#pragma unroll
    for (int t = 0; t < 2; ++t) {
        const int row = t * 64 + srow;
        cvt_store(a0[t], a1[t], &pA[t], Sbase + row * 32 + slot * 8);
        if (!diag) cvt_store(b0[t], b1[t], &pB[t], Sbase + 8192 + row * 32 + slot * 8);
    }
#pragma unroll
    for (int t = 0; t < 2; ++t) {
        const float* g = Ag + (size_t)(t * 64 + srow) * 256 + 32 + schunk * 8;
        a0[t] = *(const f32x4*)g; a1[t] = *(const f32x4*)(g + 4);
        if (!diag) {
            const float* h = Bg + (size_t)(t * 64 + srow) * 256 + 32 + schunk * 8;
            b0[t] = *(const f32x4*)h; b1[t] = *(const f32x4*)(h + 4);
        }
    }
    bar_lds();   // buf0 visible; tile-1 loads remain in flight (no vm drain)

    // ---- K-loop: 8 iters, 1 barrier each. Read buf[kk&1]; stage kk+1 into buf^1. ----
#pragma unroll
    for (int kk = 0; kk < 8; ++kk) {
        const unsigned short* Acur = Sbase + (kk & 1) * 4096;
        const unsigned short* Bcur = diag ? Acur : (Sbase + 8192 + (kk & 1) * 4096);
        bf16x8 af[4], bfr[4];
#pragma unroll
        for (int i = 0; i < 4; ++i)
            af[i] = *(const bf16x8*)(Acur + (wm + i * 16 + rl) * 32 + swl);
#pragma unroll
        for (int jj = 0; jj < 4; ++jj)
            bfr[jj] = *(const bf16x8*)(Bcur + (wn + jj * 16 + rl) * 32 + swl);
#pragma unroll
        for (int i = 0; i < 4; ++i)
#pragma unroll
            for (int jj = 0; jj < 4; ++jj)
                acc[i][jj] = __builtin_amdgcn_mfma_f32_16x16x32_bf16(
                    af[i], bfr[jj], acc[i][jj], 0, 0, 0);
        if (kk < 7) {
            const int nb = (kk + 1) & 1;
#pragma unroll
            for (int t = 0; t < 2; ++t) {       // regs hold tile kk+1 (vmcnt wait by compiler)
                const int row = t * 64 + srow;
                cvt_store(a0[t], a1[t], &pA[t], Sbase + nb * 4096 + row * 32 + slot * 8);
                if (!diag) cvt_store(b0[t], b1[t], &pB[t],
                                     Sbase + 8192 + nb * 4096 + row * 32 + slot * 8);
            }
            if (kk < 6) {                       // issue loads for tile kk+2
#pragma unroll
                for (int t = 0; t < 2; ++t) {
                    const float* g = Ag + (size_t)(t * 64 + srow) * 256 + (kk + 2) * 32 + schunk * 8;
                    a0[t] = *(const f32x4*)g; a1[t] = *(const f32x4*)(g + 4);
                    if (!diag) {
                        const float* h = Bg + (size_t)(t * 64 + srow) * 256 + (kk + 2) * 32 + schunk * 8;
                        b0[t] = *(const f32x4*)h; b1[t] = *(const f32x4*)(h + 4);
                    }
                }
            }
            bar_lds();   // writes to buf^1 visible; reads of buf done (WAR safe)
        }
    }

    // ---- row means: staged vals are raw x, mu = rowsum/256 ----
#pragma unroll
    for (int t = 0; t < 2; ++t) {
        float s = pA[t];
        s += __shfl_xor(s, 1, 64); s += __shfl_xor(s, 2, 64);
        if (schunk == 0) muA[t * 64 + srow] = s * (1.0f / 256.0f);
        if (!diag) {
            float sb = pB[t];
            sb += __shfl_xor(sb, 1, 64); sb += __shfl_xor(sb, 2, 64);
            if (schunk == 0) muB[t * 64 + srow] = sb * (1.0f / 256.0f);
        }
    }
    bar_lds();   // mu visible; last iter's frag reads drained -> Ep region reusable

    const float* muBp = diag ? muA : muB;
    float* yb = y + (size_t)b * 512 * 512;
    const float inv256 = 1.0f / 256.0f;

    // ---- single-pass epilogue: each wave writes its full acc into Ep ----
#pragma unroll
    for (int i = 0; i < 4; ++i)
#pragma unroll
        for (int jj = 0; jj < 4; ++jj) {
            const int col = wn + jj * 16 + rl;
            const float mb = muBp[col];
#pragma unroll
            for (int r = 0; r < 4; ++r) {
                const int row = wm + i * 16 + q * 4 + r;
                shf[row * 132 + col] = acc[i][jj][r] * inv256 - muA[row] * mb;
            }
        }
    bar_lds();   // Ep complete

    // normal orientation: 512B-contiguous runs, nontemporal (y is write-once)
#pragma unroll
    for (int v = 0; v < 16; ++v) {
        const int flat = v * 256 + tid;          // 0..4095
        const int rloc = flat >> 5, c4 = flat & 31;
        f32x4 val = *(const f32x4*)(shf + rloc * 132 + c4 * 4);
        __builtin_nontemporal_store(
            val, (f32x4*)(yb + (size_t)(tm * 128 + rloc) * 512 + tn * 128 + c4 * 4));
    }
    if (!diag) {  // mirror: y[col][row], read Ep transposed
#pragma unroll
        for (int v = 0; v < 16; ++v) {
            const int id   = v * 256 + tid;      // 0..4095
            const int cseg = id >> 10;           // 32-row segment
            const int cc   = (id >> 3) & 127;    // mirror row (= Ep col)
            const int g    = id & 7;             // 4-row group within segment
            f32x4 val;
#pragma unroll
            for (int e = 0; e < 4; ++e)
                val[e] = shf[(cseg * 32 + g * 4 + e) * 132 + cc];
            __builtin_nontemporal_store(
                val, (f32x4*)(yb + (size_t)(tn * 128 + cc) * 512 + tm * 128 + cseg * 32 + g * 4));
        }
    }
}

extern "C" void kernel_launch(void* const* d_in, const int* in_sizes, int n_in,
                              void* d_out, int out_size, void* d_ws, size_t ws_size,
                              hipStream_t stream) {
    const float* x = (const float*)d_in[0];
    float* yout = (float*)d_out;
    (void)d_ws; (void)ws_size;
    covpool_fused<<<640, 256, 0, stream>>>(x, yout);
}